// Round 5
// baseline (277.903 us; speedup 1.0000x reference)
//
#include <hip/hip_runtime.h>
#include <hip/hip_bf16.h>

// RelationalDistMult: B=8, N=1024, DE=128, R=8, DR=64, D=192.
// scores[b,r,n,m] = sum_k w[r,k]*node[b,n,k]*node[b,m,k] + c[b,r]
//   c[b,r] = sum_d w[r,DE+d]*rel[b,r,d]^2
// out = sigmoid(scores) f32 [B,R,N,N] = 256 MB -> HBM-write-bound
// (fill kernels measure ~7 TB/s => store roofline ~38 us).
//
// Round 8: DRAM-PAGE-LOCAL full-width row bands.
// r1-r4 evidence: three different 128-wide-tile kernels all pin at
// 4.3-4.7 TB/s effective write BW; linear model (r3->r4) shows a ~48.6 us
// store floor even at zero compute. Theory: each 4 KB output row (= one
// DRAM page) receives 8 x 512 B chunks from 8 different blocks at
// different times -> ~8 page activations/page vs 1 for the fill kernel,
// and 4 MB XCD L2 can't hold lines long enough to merge.
// Fix: block = 16 rows x FULL m=1024, all 8 r inside. Every page is
// written entirely by one block, by 16 barrier-aligned waves in one
// r-phase -> L2 assembles complete pages, evicts near-sequentially.
//  - forfeits symmetry (MFMA x1.78 = ~8.6 us, overlappable)
//  - NO LDS staging at all: m-fragments direct global->reg (lanes
//    lr/lr+16/lr+32/lr+48 consume the 4 quarters of each 128 B line ->
//    line-granular coalescing), converted to bf16 once, reused for all 8 r
//  - n-fragments raw f32 in regs; per-r in-register rescale via
//    v_cvt_pk_bf16_f32 (RNE -> bitwise-identical numerics to rdm7)
//  - raw s_barrier per r (no vmcnt drain) keeps waves page-aligned
//  - grid 512 x 1024 thr (16 waves, wave = 16 rows x 64 cols), 2 blocks/CU

typedef __attribute__((ext_vector_type(8))) short bf16x8;
typedef __attribute__((ext_vector_type(4))) float f32x4;

constexpr int Bc = 8, Nc = 1024, DEc = 128, Rc = 8, DRc = 64, Dc = 192;

static __device__ __forceinline__ float fast_sigmoid(float x) {
    // sigmoid(x) = 1 / (1 + 2^(-x*log2e)); v_exp_f32 computes 2^x.
    float e;
    asm("v_exp_f32 %0, %1" : "=v"(e) : "v"(x * -1.44269504f));
    float s;
    asm("v_rcp_f32 %0, %1" : "=v"(s) : "v"(e + 1.0f));
    return s;
}

static __device__ __forceinline__ bf16x8 cvt8(const f32x4 a, const f32x4 b) {
    union { bf16x8 v; unsigned u[4]; } r;
    asm("v_cvt_pk_bf16_f32 %0, %1, %2" : "=v"(r.u[0]) : "v"(a[0]), "v"(a[1]));
    asm("v_cvt_pk_bf16_f32 %0, %1, %2" : "=v"(r.u[1]) : "v"(a[2]), "v"(a[3]));
    asm("v_cvt_pk_bf16_f32 %0, %1, %2" : "=v"(r.u[2]) : "v"(b[0]), "v"(b[1]));
    asm("v_cvt_pk_bf16_f32 %0, %1, %2" : "=v"(r.u[3]) : "v"(b[2]), "v"(b[3]));
    return r.v;
}

__global__ __launch_bounds__(1024, 8) void rdm8(
    const float* __restrict__ node,   // [B,N,DE]
    const float* __restrict__ rel,    // [B,R,DR]
    const float* __restrict__ w,      // [R,D]
    float* __restrict__ out)          // [B,R,N,N]
{
    __shared__ float Cs[8];

    const int b  = blockIdx.x & 7;          // XCD-major: node[b] L2-resident
    const int n0 = (blockIdx.x >> 3) << 4;  // 16-row output band

    const int tid  = threadIdx.x;
    const int lane = tid & 63;
    const int wid  = tid >> 6;              // 0..15; wave owns cols wid*64..+63
    const int lr   = lane & 15;
    const int lk   = (lane >> 4) * 8;

    const float* nodeb = node + (long)b * Nc * DEc;

    // --- c[b,0..7]: wave 0, 8 lanes per r, 8 d-elems per lane ---
    if (tid < 64) {
        const int r8 = lane >> 3;
        const int d0 = (lane & 7) * 8;
        const float* wp = w + r8 * Dc + DEc + d0;
        const float* rp = rel + ((long)b * Rc + r8) * DRc + d0;
        float cv = 0.f;
        #pragma unroll
        for (int j = 0; j < 8; ++j) { const float rv = rp[j]; cv += wp[j] * rv * rv; }
        cv += __shfl_xor(cv, 1, 64);
        cv += __shfl_xor(cv, 2, 64);
        cv += __shfl_xor(cv, 4, 64);
        if ((lane & 7) == 0) Cs[r8] = cv;
    }

    // --- m-side fragments: direct global->reg, bf16 once, reused all 8 r.
    // MFMA A layout: lane holds m-row (cg*16+lr), k-slice (lane>>4)*8.
    // Lane groups lk=0/8/16/24 + the a0/a1 pair fully consume each 128 B
    // line of the 4 rows' k-slices -> line-granular coalescing from L2.
    bf16x8 afr[4][4];                 // [cg][kk]
    #pragma unroll
    for (int cg = 0; cg < 4; ++cg) {
        const float* mp = nodeb + (long)(wid * 64 + cg * 16 + lr) * DEc;
        #pragma unroll
        for (int kk = 0; kk < 4; ++kk) {
            const f32x4 a0 = *(const f32x4*)(mp + kk * 32 + lk);
            const f32x4 a1 = *(const f32x4*)(mp + kk * 32 + lk + 4);
            afr[cg][kk] = cvt8(a0, a1);
        }
    }

    // --- n-side raw f32 fragments (band rows n0..n0+15) ---
    f32x4 braw[4][2];                 // [kk][half]
    {
        const float* np = nodeb + (long)(n0 + lr) * DEc;
        #pragma unroll
        for (int kk = 0; kk < 4; ++kk) {
            braw[kk][0] = *(const f32x4*)(np + kk * 32 + lk);
            braw[kk][1] = *(const f32x4*)(np + kk * 32 + lk + 4);
        }
    }

    __syncthreads();                  // Cs ready

    float* planeb = out + (long)b * Rc * Nc * Nc + (long)n0 * Nc + wid * 64;

    #pragma unroll 1
    for (int r = 0; r < Rc; ++r) {
        const float c = Cs[r];
        const float* wr = w + r * Dc;

        // scale n-fragments in-register for this r (RNE, same numerics as f2bf)
        bf16x8 bfr[4];
        #pragma unroll
        for (int kk = 0; kk < 4; ++kk) {
            const f32x4 w0 = *(const f32x4*)(wr + kk * 32 + lk);      // broadcast
            const f32x4 w1 = *(const f32x4*)(wr + kk * 32 + lk + 4);
            bfr[kk] = cvt8(braw[kk][0] * w0, braw[kk][1] * w1);
        }

        f32x4 acc[4] = {};
        #pragma unroll
        for (int kk = 0; kk < 4; ++kk)
            #pragma unroll
            for (int cg = 0; cg < 4; ++cg)
                acc[cg] = __builtin_amdgcn_mfma_f32_16x16x32_bf16(
                    afr[cg][kk], bfr[kk], acc[cg], 0, 0, 0);

        // store: D layout -> n = n0+lr, m = wid*64 + cg*16 + (lane>>4)*4 + j.
        // 16 waves x 4 cg cover each 4 KB row completely within this r-phase.
        float* outr = planeb + ((long)r << 20);
        #pragma unroll
        for (int cg = 0; cg < 4; ++cg) {
            f32x4 v;
            v[0] = fast_sigmoid(acc[cg][0] + c);
            v[1] = fast_sigmoid(acc[cg][1] + c);
            v[2] = fast_sigmoid(acc[cg][2] + c);
            v[3] = fast_sigmoid(acc[cg][3] + c);
            *(f32x4*)(outr + (long)lr * Nc + cg * 16 + (lane >> 4) * 4) = v;
        }

        // raw barrier (no vmcnt drain): keep waves page-aligned across r
        __builtin_amdgcn_s_barrier();
    }
}

extern "C" void kernel_launch(void* const* d_in, const int* in_sizes, int n_in,
                              void* d_out, int out_size, void* d_ws, size_t ws_size,
                              hipStream_t stream) {
    const float* node = (const float*)d_in[0];  // [8,1024,128]
    const float* rel  = (const float*)d_in[1];  // [8,8,64]
    const float* w    = (const float*)d_in[2];  // [8,192]
    float* out = (float*)d_out;                 // [8,8,1024,1024]

    rdm8<<<512, 1024, 0, stream>>>(node, rel, w, out);
}

// Round 6
// 92.989 us; speedup vs baseline: 2.9886x; 2.9886x over previous
//
#include <hip/hip_runtime.h>
#include <hip/hip_bf16.h>

// RelationalDistMult: B=8, N=1024, DE=128, R=8, DR=64, D=192.
// scores[b,r,n,m] = sum_k w[r,k]*node[b,n,k]*node[b,m,k] + c[b,r]
//   c[b,r] = sum_d w[r,DE+d]*rel[b,r,d]^2
// out = sigmoid(scores) f32 [B,R,N,N] = 256 MB -> HBM-write-bound
// (fill kernels measure ~7 TB/s => store roofline ~38 us).
//
// Round 9 = round-8 band structure with the spill bug fixed.
// r5 post-mortem: __launch_bounds__(1024,8) capped VGPR at 32 vs ~150 demand
// -> 563 MB scratch FETCH + 140 MB scratch WRITE, 284 us. The page-locality
// theory was never tested.
// Fix:
//  - __launch_bounds__(1024,1): VGPR cap 128, 1 block/CU (16 waves).
//  - n-side raw f32 moves regs -> padded LDS [16][132] (2-way bank aliasing
//    = free); per r re-read 32 B/lane + in-register rescale via
//    v_cvt_pk_bf16_f32 (RNE path numerically verified by r5's pass).
//  - m-side afr: 64 VGPR bf16, global->reg once, reused for all 8 r;
//    each (cg,kk) load pair consumes complete 128 B lines.
//  - register demand ~120 < 128 cap -> no scratch.
// Band structure unchanged: block = 16 output rows x full m=1024, all 8 r;
// every 4 KB output row (= DRAM page) written entirely by this block within
// one barrier-aligned r-phase -> L2 assembles complete pages, evicts
// near-sequentially (the fill-kernel pattern).

typedef __attribute__((ext_vector_type(8))) short bf16x8;
typedef __attribute__((ext_vector_type(4))) float f32x4;

constexpr int Bc = 8, Nc = 1024, DEc = 128, Rc = 8, DRc = 64, Dc = 192;

static __device__ __forceinline__ float fast_sigmoid(float x) {
    // sigmoid(x) = 1 / (1 + 2^(-x*log2e)); v_exp_f32 computes 2^x.
    float e;
    asm("v_exp_f32 %0, %1" : "=v"(e) : "v"(x * -1.44269504f));
    float s;
    asm("v_rcp_f32 %0, %1" : "=v"(s) : "v"(e + 1.0f));
    return s;
}

static __device__ __forceinline__ bf16x8 cvt8(const f32x4 a, const f32x4 b) {
    union { bf16x8 v; unsigned u[4]; } r;
    asm("v_cvt_pk_bf16_f32 %0, %1, %2" : "=v"(r.u[0]) : "v"(a[0]), "v"(a[1]));
    asm("v_cvt_pk_bf16_f32 %0, %1, %2" : "=v"(r.u[1]) : "v"(a[2]), "v"(a[3]));
    asm("v_cvt_pk_bf16_f32 %0, %1, %2" : "=v"(r.u[2]) : "v"(b[0]), "v"(b[1]));
    asm("v_cvt_pk_bf16_f32 %0, %1, %2" : "=v"(r.u[3]) : "v"(b[2]), "v"(b[3]));
    return r.v;
}

__global__ __launch_bounds__(1024, 1) void rdm9(
    const float* __restrict__ node,   // [B,N,DE]
    const float* __restrict__ rel,    // [B,R,DR]
    const float* __restrict__ w,      // [R,D]
    float* __restrict__ out)          // [B,R,N,N]
{
    __shared__ float Ns[16 * 132];    // raw n-band f32, padded (+4 words/row)
    __shared__ float Cs[8];

    const int b  = blockIdx.x & 7;          // XCD-major: node[b] L2-resident
    const int n0 = (blockIdx.x >> 3) << 4;  // 16-row output band

    const int tid  = threadIdx.x;
    const int lane = tid & 63;
    const int wid  = tid >> 6;              // 0..15; wave owns cols wid*64..+63
    const int lr   = lane & 15;
    const int lkw  = (lane >> 4) * 8;       // k word offset within 32-k step

    const float* nodeb = node + (long)b * Nc * DEc;

    // --- c[b,0..7]: wave 0, 8 lanes per r, 8 d-elems per lane ---
    if (tid < 64) {
        const int r8 = lane >> 3;
        const int d0 = (lane & 7) * 8;
        const float* wp = w + r8 * Dc + DEc + d0;
        const float* rp = rel + ((long)b * Rc + r8) * DRc + d0;
        float cv = 0.f;
        #pragma unroll
        for (int j = 0; j < 8; ++j) { const float rv = rp[j]; cv += wp[j] * rv * rv; }
        cv += __shfl_xor(cv, 1, 64);
        cv += __shfl_xor(cv, 2, 64);
        cv += __shfl_xor(cv, 4, 64);
        if ((lane & 7) == 0) Cs[r8] = cv;
    }

    // --- stage raw n-band f32 -> padded LDS (once; reused all 8 r) ---
    if (tid < 512) {
        const int row = tid >> 5;           // 0..15
        const int c4  = (tid & 31) * 4;     // 0..124
        const float4 v = *(const float4*)(nodeb + (long)(n0 + row) * DEc + c4);
        *(float4*)&Ns[row * 132 + c4] = v;
    }

    // --- m-side fragments: global->reg, bf16 once, reused all 8 r.
    // Lane (lr, lane>>4) reads 32 contiguous B at byte (lane>>4)*32 of the
    // 128 B line holding row (wid*64+cg*16+lr)'s kk-slice -> full-line use.
    bf16x8 afr[4][4];                 // [cg][kk] : 64 VGPRs
    #pragma unroll
    for (int cg = 0; cg < 4; ++cg) {
        const float* mp = nodeb + (long)(wid * 64 + cg * 16 + lr) * DEc;
        #pragma unroll
        for (int kk = 0; kk < 4; ++kk) {
            const f32x4 a0 = *(const f32x4*)(mp + kk * 32 + lkw);
            const f32x4 a1 = *(const f32x4*)(mp + kk * 32 + lkw + 4);
            afr[cg][kk] = cvt8(a0, a1);
        }
    }

    __syncthreads();                  // Cs + Ns ready

    float* planeb = out + (long)b * Rc * Nc * Nc + (long)n0 * Nc + wid * 64;

    #pragma unroll 1
    for (int r = 0; r < Rc; ++r) {
        const float c = Cs[r];
        const float* wr = w + r * Dc;

        f32x4 acc[4] = {};
        #pragma unroll
        for (int kk = 0; kk < 4; ++kk) {
            // n-fragment: re-read raw f32 from LDS, rescale for this r (RNE)
            const f32x4 w0 = *(const f32x4*)(wr + kk * 32 + lkw);   // broadcast
            const f32x4 w1 = *(const f32x4*)(wr + kk * 32 + lkw + 4);
            const f32x4 x0 = *(const f32x4*)&Ns[lr * 132 + kk * 32 + lkw];
            const f32x4 x1 = *(const f32x4*)&Ns[lr * 132 + kk * 32 + lkw + 4];
            const bf16x8 bfr = cvt8(x0 * w0, x1 * w1);
            #pragma unroll
            for (int cg = 0; cg < 4; ++cg)
                acc[cg] = __builtin_amdgcn_mfma_f32_16x16x32_bf16(
                    afr[cg][kk], bfr, acc[cg], 0, 0, 0);
        }

        // store: n = n0+lr, m = wid*64 + cg*16 + (lane>>4)*4 + j.
        // 16 waves x 4 cg cover each 4 KB row completely within this r-phase.
        float* outr = planeb + ((long)r << 20);
        #pragma unroll
        for (int cg = 0; cg < 4; ++cg) {
            f32x4 v;
            v[0] = fast_sigmoid(acc[cg][0] + c);
            v[1] = fast_sigmoid(acc[cg][1] + c);
            v[2] = fast_sigmoid(acc[cg][2] + c);
            v[3] = fast_sigmoid(acc[cg][3] + c);
            *(f32x4*)(outr + (long)lr * Nc + cg * 16 + (lane >> 4) * 4) = v;
        }

        // raw barrier (no vmcnt drain): keep waves page-aligned across r;
        // stores stay in flight and overlap next r's compute.
        __builtin_amdgcn_s_barrier();
    }
}

extern "C" void kernel_launch(void* const* d_in, const int* in_sizes, int n_in,
                              void* d_out, int out_size, void* d_ws, size_t ws_size,
                              hipStream_t stream) {
    const float* node = (const float*)d_in[0];  // [8,1024,128]
    const float* rel  = (const float*)d_in[1];  // [8,8,64]
    const float* w    = (const float*)d_in[2];  // [8,192]
    float* out = (float*)d_out;                 // [8,8,1024,1024]

    rdm9<<<512, 1024, 0, stream>>>(node, rel, w, out);
}

// Round 7
// 55.889 us; speedup vs baseline: 4.9724x; 1.6638x over previous
//
#include <hip/hip_runtime.h>
#include <hip/hip_bf16.h>

// RelationalDistMult: B=8, N=1024, DE=128, R=8, DR=64, D=192.
// scores[b,r,n,m] = sum_k w[r,k]*node[b,n,k]*node[b,m,k] + c[b,r]
//   c[b,r] = sum_d w[r,DE+d]*rel[b,r,d]^2
// out = sigmoid(scores) f32 [B,R,N,N] = 256 MB -> HBM-write-bound
// (fill kernels ~7 TB/s => store roofline ~38 us; best so far rdm7 56.8).
//
// Round 10: symmetric all-r 64x64 blocks -> continuous store duty cycle.
// Evidence: fills hit 7 TB/s at 3.4 waves/CU (occupancy not the limiter);
// rdm7 stores only in one end-of-block burst (duty cycle is the limiter);
// bands (r5/r6) refuted; symmetry (r4) and staging-reuse (r2) each verified.
// Design:
//  - grid = 8 b x 136 upper-tri 64-tile pairs = 1088 blocks, 256 thr,
//    4 waves of 32(m)x32(n). b = blockIdx&7 (XCD-pinned, node[b] L2-resident).
//  - stage once per block: n-slab raw f32 -> LDS [64][132] (2-way bank
//    aliasing = free); m-slab bf16 A-frags global->reg (afr[2][4]).
//  - r-loop with ZERO barriers: per r, re-read n-frags from LDS, rescale
//    in-register (f32 mul + v_cvt_pk_bf16_f32 RNE -- bitwise-identical
//    numerics to rdm7's stage path), 16 MFMA, sigmoid, stores.
//  - stores per wave per r: 4 direct f32x4 + (offdiag) 4 transposed f32x4
//    via wave-private LDS bounce [32][37] (pad 37: conflict-free write
//    (5*lr distinct mod 32) and gather-read (20*(l&7)+(l>>3) distinct)).
//  - stores recur EVERY r-phase, no inter-phase barrier -> 12 waves/CU
//    stream ~continuously; per phase: ~3500 cy store drain vs ~1700 cy
//    compute -> write pipe stays backed up.
//  - VGPR ~115 (cap 168 via launch_bounds(256,3)); LDS 52.8 KB -> 3 blk/CU.

typedef __attribute__((ext_vector_type(8))) short bf16x8;
typedef __attribute__((ext_vector_type(4))) float f32x4;

constexpr int Bc = 8, Nc = 1024, DEc = 128, Rc = 8, DRc = 64, Dc = 192;

static __device__ __forceinline__ float fast_sigmoid(float x) {
    // sigmoid(x) = 1 / (1 + 2^(-x*log2e)); v_exp_f32 computes 2^x.
    float e;
    asm("v_exp_f32 %0, %1" : "=v"(e) : "v"(x * -1.44269504f));
    float s;
    asm("v_rcp_f32 %0, %1" : "=v"(s) : "v"(e + 1.0f));
    return s;
}

static __device__ __forceinline__ bf16x8 cvt8(const f32x4 a, const f32x4 b) {
    union { bf16x8 v; unsigned u[4]; } r;
    asm("v_cvt_pk_bf16_f32 %0, %1, %2" : "=v"(r.u[0]) : "v"(a[0]), "v"(a[1]));
    asm("v_cvt_pk_bf16_f32 %0, %1, %2" : "=v"(r.u[1]) : "v"(a[2]), "v"(a[3]));
    asm("v_cvt_pk_bf16_f32 %0, %1, %2" : "=v"(r.u[2]) : "v"(b[0]), "v"(b[1]));
    asm("v_cvt_pk_bf16_f32 %0, %1, %2" : "=v"(r.u[3]) : "v"(b[2]), "v"(b[3]));
    return r.v;
}

__global__ __launch_bounds__(256, 3) void rdm10(
    const float* __restrict__ node,   // [B,N,DE]
    const float* __restrict__ rel,    // [B,R,DR]
    const float* __restrict__ w,      // [R,D]
    float* __restrict__ out)          // [B,R,N,N]
{
    __shared__ float Ns[64 * 132];        // raw n-slab f32, stride 132
    __shared__ float tb[4 * 32 * 37];     // per-wave transpose bounce
    __shared__ float Cs[8];

    const int lin = blockIdx.x;
    const int b   = lin & 7;              // XCD-major
    int tp = lin >> 3;                    // 0..135 upper-tri pair over 16 tiles

    int i = 0, base = 0;
    while (tp >= base + (16 - i)) { base += 16 - i; ++i; }
    const int j = i + (tp - base);
    const int n0 = i * 64;
    const int m0 = j * 64;
    const bool offd = (i != j);

    const int tid  = threadIdx.x;
    const int lane = tid & 63;
    const int wid  = tid >> 6;            // 0..3
    const int wm   = (wid >> 1) * 32;     // wave m offset in 64-tile
    const int wn   = (wid & 1) * 32;      // wave n offset in 64-tile
    const int lr   = lane & 15;
    const int lkw  = (lane >> 4) * 8;     // k word offset within 32-k step

    const float* nodeb = node + (long)b * Nc * DEc;

    // --- c[b,0..7]: wave 0, 8 lanes per r, 8 d-elems per lane ---
    if (tid < 64) {
        const int r8 = lane >> 3;
        const int d0 = (lane & 7) * 8;
        const float* wp = w + r8 * Dc + DEc + d0;
        const float* rp = rel + ((long)b * Rc + r8) * DRc + d0;
        float cv = 0.f;
        #pragma unroll
        for (int q = 0; q < 8; ++q) { const float rv = rp[q]; cv += wp[q] * rv * rv; }
        cv += __shfl_xor(cv, 1, 64);
        cv += __shfl_xor(cv, 2, 64);
        cv += __shfl_xor(cv, 4, 64);
        if ((lane & 7) == 0) Cs[r8] = cv;
    }

    // --- m-side A-fragments: global->reg, bf16 once, reused all 8 r ---
    bf16x8 afr[2][4];                     // [mi][kk]
    #pragma unroll
    for (int mi = 0; mi < 2; ++mi) {
        const float* mp = nodeb + (long)(m0 + wm + mi * 16 + lr) * DEc;
        #pragma unroll
        for (int kk = 0; kk < 4; ++kk) {
            const f32x4 a0 = *(const f32x4*)(mp + kk * 32 + lkw);
            const f32x4 a1 = *(const f32x4*)(mp + kk * 32 + lkw + 4);
            afr[mi][kk] = cvt8(a0, a1);
        }
    }

    // --- stage raw n-slab f32 -> LDS (once; reused all 8 r) ---
    {
        const int col4 = (tid & 31) * 4;  // 0..124
        const int row0 = tid >> 5;        // 0..7
        #pragma unroll
        for (int p = 0; p < 8; ++p) {
            const int row = row0 + p * 8;
            const float4 v = *(const float4*)(nodeb + (long)(n0 + row) * DEc + col4);
            *(float4*)&Ns[row * 132 + col4] = v;
        }
    }
    __syncthreads();                      // Cs + Ns ready; last barrier.

    float* tbw = tb + wid * (32 * 37);

    #pragma unroll 1
    for (int r = 0; r < Rc; ++r) {
        const float c = Cs[r];
        const float* wr = w + r * Dc;

        // n-side B-fragments: LDS raw + in-register rescale (RNE)
        bf16x8 bfr[2][4];                 // [ni][kk]
        #pragma unroll
        for (int ni = 0; ni < 2; ++ni) {
            const int rowB = wn + ni * 16 + lr;
            #pragma unroll
            for (int kk = 0; kk < 4; ++kk) {
                const f32x4 w0 = *(const f32x4*)(wr + kk * 32 + lkw);
                const f32x4 w1 = *(const f32x4*)(wr + kk * 32 + lkw + 4);
                const f32x4 x0 = *(const f32x4*)&Ns[rowB * 132 + kk * 32 + lkw];
                const f32x4 x1 = *(const f32x4*)&Ns[rowB * 132 + kk * 32 + lkw + 4];
                bfr[ni][kk] = cvt8(x0 * w0, x1 * w1);
            }
        }

        f32x4 acc[2][2] = {};
        #pragma unroll
        for (int kk = 0; kk < 4; ++kk)
            #pragma unroll
            for (int mi = 0; mi < 2; ++mi)
                #pragma unroll
                for (int ni = 0; ni < 2; ++ni)
                    acc[mi][ni] = __builtin_amdgcn_mfma_f32_16x16x32_bf16(
                        afr[mi][kk], bfr[ni][kk], acc[mi][ni], 0, 0, 0);

        float* plane = out + ((long)(b * Rc + r) << 20);

        // direct stores (+ bounce write for the transposed copy)
        #pragma unroll
        for (int mi = 0; mi < 2; ++mi) {
            #pragma unroll
            for (int ni = 0; ni < 2; ++ni) {
                const int nn = n0 + wn + ni * 16 + lr;
                const int mm = m0 + wm + mi * 16 + (lane >> 4) * 4;
                f32x4 v;
                v[0] = fast_sigmoid(acc[mi][ni][0] + c);
                v[1] = fast_sigmoid(acc[mi][ni][1] + c);
                v[2] = fast_sigmoid(acc[mi][ni][2] + c);
                v[3] = fast_sigmoid(acc[mi][ni][3] + c);
                *(f32x4*)(plane + (long)nn * Nc + mm) = v;
                if (offd) {
                    const int n_t = ni * 16 + lr;
                    const int m_t = mi * 16 + (lane >> 4) * 4;
                    *(f32x4*)&tbw[n_t * 37 + m_t] = v;
                }
            }
        }

        // transposed stores: out[m, n] from wave-private bounce (no barrier)
        if (offd) {
            asm volatile("s_waitcnt lgkmcnt(0)" ::: "memory");
            #pragma unroll
            for (int p = 0; p < 4; ++p) {
                const int m_t = p * 8 + (lane >> 3);   // 0..31
                const int n_t = (lane & 7) * 4;        // 0..28
                f32x4 v;
                v[0] = tbw[(n_t + 0) * 37 + m_t];
                v[1] = tbw[(n_t + 1) * 37 + m_t];
                v[2] = tbw[(n_t + 2) * 37 + m_t];
                v[3] = tbw[(n_t + 3) * 37 + m_t];
                *(f32x4*)(plane + (long)(m0 + wm + m_t) * Nc + (n0 + wn + n_t)) = v;
            }
        }
    }
}

extern "C" void kernel_launch(void* const* d_in, const int* in_sizes, int n_in,
                              void* d_out, int out_size, void* d_ws, size_t ws_size,
                              hipStream_t stream) {
    const float* node = (const float*)d_in[0];  // [8,1024,128]
    const float* rel  = (const float*)d_in[1];  // [8,8,64]
    const float* w    = (const float*)d_in[2];  // [8,192]
    float* out = (float*)d_out;                 // [8,8,1024,1024]

    rdm10<<<Bc * 136, 256, 0, stream>>>(node, rel, w, out);
}